// Round 4
// baseline (201.582 us; speedup 1.0000x reference)
//
#include <hip/hip_runtime.h>

// Problem constants (fixed by setup_inputs)
constexpr int kB  = 4;
constexpr int kNp = 8192;
constexpr int kNq = 2048;
constexpr int kK  = 32;   // max samples per query
constexpr float kR2 = (float)(0.2 * 0.2);   // matches numpy f32(radius*radius)

// Native clang vector types (HIP's float4/int4 are classes, which
// __builtin_nontemporal_store rejects).
typedef float v4f __attribute__((ext_vector_type(4)));
typedef int   v4i __attribute__((ext_vector_type(4)));

// ---------------------------------------------------------------------------
// Kernel 1: ball query. One wave per query, AoS coord reads (lane p reads
// bytes [12p,12p+12) -> 768B contiguous per chunk, fully coalesced). Scans in
// groups of 4x64 points with one uniform early-exit per group (8+ independent
// loads in flight). Ballot + prefix-popcount preserves exact
// first-K-in-index-order semantics. Emits resolved idxs and the 3
// centered-coords output channels.
// ---------------------------------------------------------------------------
__global__ __launch_bounds__(256) void ball_query_kernel(
    const float* __restrict__ coords,   // [B][Np][3]
    const float* __restrict__ queries,  // [B][Nq][3]
    int* __restrict__ idxs,             // [B*Nq][K] (resolved, fill applied)
    float* __restrict__ out)            // full output tensor
{
    const int wave = (int)((blockIdx.x * blockDim.x + threadIdx.x) >> 6);
    const int lane = threadIdx.x & 63;
    const int w    = threadIdx.x >> 6;          // wave within block (0..3)
    const int b    = wave >> 11;                // / Nq
    const int q    = wave & (kNq - 1);

    const float qx = queries[(b * kNq + q) * 3 + 0];
    const float qy = queries[(b * kNq + q) * 3 + 1];
    const float qz = queries[(b * kNq + q) * 3 + 2];

    const float* __restrict__ cb = coords + (size_t)b * kNp * 3;

    __shared__ int s_idx[4][kK];   // per-wave private region; no barrier needed

    const unsigned long long lt = (1ull << lane) - 1ull;
    int cnt = 0;
    for (int base = 0; base < kNp; base += 256) {
#pragma unroll
        for (int j = 0; j < 4; ++j) {
            const int p = base + j * 64 + lane;
            const float cx = cb[p * 3 + 0];
            const float cy = cb[p * 3 + 1];
            const float cz = cb[p * 3 + 2];
            // exact f32 per-op arithmetic (no fma contraction) to match numpy
            const float dx = __fsub_rn(qx, cx);
            const float dy = __fsub_rn(qy, cy);
            const float dz = __fsub_rn(qz, cz);
            const float d2 = __fadd_rn(
                __fadd_rn(__fmul_rn(dx, dx), __fmul_rn(dy, dy)),
                __fmul_rn(dz, dz));
            const bool in_ball = d2 < kR2;
            const unsigned long long m = __ballot(in_ball);
            if (in_ball) {
                const int slot = cnt + __popcll(m & lt);
                if (slot < kK) s_idx[w][slot] = p;
            }
            cnt += __popcll(m);              // wave-uniform
        }
        if (cnt >= kK) break;                // uniform branch, checked per 256
    }

    if (lane < kK) {
        int v;
        if (cnt == 0)        v = 0;
        else if (lane < cnt) v = s_idx[w][lane];
        else                 v = s_idx[w][0];       // fill with first valid
        idxs[(size_t)wave * kK + lane] = v;

        // centered-coords output channels 0..2 of grouped_features
        const int k = lane;
        float* gf = out + ((size_t)(b * 67) * kNq + q) * kK + k;
        gf[(size_t)0 * kNq * kK] = __fsub_rn(cb[v * 3 + 0], qx);
        gf[(size_t)1 * kNq * kK] = __fsub_rn(cb[v * 3 + 1], qy);
        gf[(size_t)2 * kNq * kK] = __fsub_rn(cb[v * 3 + 2], qz);
    }
}

// ---------------------------------------------------------------------------
// Kernel 2: scatter-free gather. One block per (b, source-channel, q-half):
// stage the 32KB channel row in LDS (coalesced 16B loads), then
// out[c][q][k] = row[idx] with 16B idx loads + nontemporal 16B stores
// (perfectly coalesced, write-once stream bypasses L2).
// Grid = B * 128 * 2 = 1024 blocks -> 4 blocks/CU (LDS-limited max is 5).
// ---------------------------------------------------------------------------
__global__ __launch_bounds__(256) void gather_kernel(
    const float* __restrict__ feat,   // [B][64][Np]
    const float* __restrict__ temb,   // [B][64][Np]
    const int*   __restrict__ idxs,   // [B*Nq][K] resolved
    float* __restrict__ out)
{
    const int blk = blockIdx.x;        // 0 .. 1023
    const int h   = blk & 1;           // query-range half
    const int j   = (blk >> 1) & 127;  // 0..63 feat, 64..127 temb
    const int b   = blk >> 8;

    const float* src;
    float* dst;
    if (j < 64) {
        src = feat + ((size_t)b * 64 + j) * kNp;
        dst = out + (size_t)(b * 67 + 3 + j) * (kNq * kK);
    } else {
        src = temb + ((size_t)b * 64 + (j - 64)) * kNp;
        dst = out + (size_t)kB * 67 * kNq * kK
                  + (size_t)(b * 64 + (j - 64)) * (kNq * kK);
    }

    __shared__ float row[kNp];         // 32 KB
    {
        const v4f* s4 = (const v4f*)src;
        v4f* r4 = (v4f*)row;
#pragma unroll
        for (int i = 0; i < kNp / 4 / 256; ++i)     // 8 iters
            r4[i * 256 + threadIdx.x] = s4[i * 256 + threadIdx.x];
    }
    __syncthreads();

    const v4i* id4 = (const v4i*)(idxs + (size_t)b * kNq * kK);
    v4f* d4 = (v4f*)dst;
    constexpr int half4 = kNq * kK / 4 / 2;         // 8192 per half
    const int e0 = h * half4;
#pragma unroll 4
    for (int e = threadIdx.x; e < half4; e += 256) {
        const v4i id = id4[e0 + e];
        v4f v;
        v.x = row[id.x];
        v.y = row[id.y];
        v.z = row[id.z];
        v.w = row[id.w];
        __builtin_nontemporal_store(v, &d4[e0 + e]);
    }
}

// ---------------------------------------------------------------------------
extern "C" void kernel_launch(void* const* d_in, const int* in_sizes, int n_in,
                              void* d_out, int out_size, void* d_ws, size_t ws_size,
                              hipStream_t stream) {
    const float* coords  = (const float*)d_in[0];  // [B,Np,3]
    const float* feats   = (const float*)d_in[1];  // [B,64,Np]
    const float* temb    = (const float*)d_in[2];  // [B,64,Np]
    const float* queries = (const float*)d_in[3];  // [B,Nq,3]
    float* out = (float*)d_out;

    int* idxs = (int*)d_ws;                        // 1 MB scratch

    ball_query_kernel<<<kB * kNq / 4, 256, 0, stream>>>(coords, queries, idxs, out);
    gather_kernel<<<kB * 128 * 2, 256, 0, stream>>>(feats, temb, idxs, out);
}

// Round 5
// 199.199 us; speedup vs baseline: 1.0120x; 1.0120x over previous
//
#include <hip/hip_runtime.h>

// Problem constants (fixed by setup_inputs)
constexpr int kB  = 4;
constexpr int kNp = 8192;
constexpr int kNq = 2048;
constexpr int kK  = 32;   // max samples per query
constexpr float kR2 = (float)(0.2 * 0.2);   // matches numpy f32(radius*radius)

// Native clang vector types (HIP's float4/int4 are classes; ext-vectors map
// directly onto dwordx4 loads/stores).
typedef float v4f __attribute__((ext_vector_type(4)));
typedef int   v4i __attribute__((ext_vector_type(4)));

// ---------------------------------------------------------------------------
// Kernel 1: ball query. One wave per query, AoS coord reads (lane p reads
// bytes [12p,12p+12) -> 768B contiguous per 64-pt chunk; coords are 96KB per
// batch, L1/L2-resident after first touch). Scans in groups of 4x64 points
// with one uniform early-exit per group (12 independent loads in flight).
// Ballot + prefix-popcount preserves exact first-K-in-index-order semantics.
// Emits resolved idxs and the 3 centered-coords output channels.
// ---------------------------------------------------------------------------
__global__ __launch_bounds__(256) void ball_query_kernel(
    const float* __restrict__ coords,   // [B][Np][3]
    const float* __restrict__ queries,  // [B][Nq][3]
    int* __restrict__ idxs,             // [B*Nq][K] (resolved, fill applied)
    float* __restrict__ out)            // full output tensor
{
    const int wave = (int)((blockIdx.x * blockDim.x + threadIdx.x) >> 6);
    const int lane = threadIdx.x & 63;
    const int w    = threadIdx.x >> 6;          // wave within block (0..3)
    const int b    = wave >> 11;                // / Nq
    const int q    = wave & (kNq - 1);

    const float qx = queries[(b * kNq + q) * 3 + 0];
    const float qy = queries[(b * kNq + q) * 3 + 1];
    const float qz = queries[(b * kNq + q) * 3 + 2];

    const float* __restrict__ cb = coords + (size_t)b * kNp * 3;

    __shared__ int s_idx[4][kK];   // per-wave private region; no barrier needed

    const unsigned long long lt = (1ull << lane) - 1ull;
    int cnt = 0;
    for (int base = 0; base < kNp; base += 256) {
#pragma unroll
        for (int j = 0; j < 4; ++j) {
            const int p = base + j * 64 + lane;
            const float cx = cb[p * 3 + 0];
            const float cy = cb[p * 3 + 1];
            const float cz = cb[p * 3 + 2];
            // exact f32 per-op arithmetic (no fma contraction) to match numpy
            const float dx = __fsub_rn(qx, cx);
            const float dy = __fsub_rn(qy, cy);
            const float dz = __fsub_rn(qz, cz);
            const float d2 = __fadd_rn(
                __fadd_rn(__fmul_rn(dx, dx), __fmul_rn(dy, dy)),
                __fmul_rn(dz, dz));
            const bool in_ball = d2 < kR2;
            const unsigned long long m = __ballot(in_ball);
            if (in_ball) {
                const int slot = cnt + __popcll(m & lt);
                if (slot < kK) s_idx[w][slot] = p;
            }
            cnt += __popcll(m);              // wave-uniform
        }
        if (cnt >= kK) break;                // uniform branch, checked per 256
    }

    if (lane < kK) {
        int v;
        if (cnt == 0)        v = 0;
        else if (lane < cnt) v = s_idx[w][lane];
        else                 v = s_idx[w][0];       // fill with first valid
        idxs[(size_t)wave * kK + lane] = v;

        // centered-coords output channels 0..2 of grouped_features
        const int k = lane;
        float* gf = out + ((size_t)(b * 67) * kNq + q) * kK + k;
        gf[(size_t)0 * kNq * kK] = __fsub_rn(cb[v * 3 + 0], qx);
        gf[(size_t)1 * kNq * kK] = __fsub_rn(cb[v * 3 + 1], qy);
        gf[(size_t)2 * kNq * kK] = __fsub_rn(cb[v * 3 + 2], qz);
    }
}

// ---------------------------------------------------------------------------
// Kernel 2: scatter-free gather (round-2 proven config). One block per
// (b, source-channel): stage the 32KB channel row in LDS (coalesced 16B
// loads), then out[c][q][k] = row[idx] with 16B idx loads + plain 16B stores
// (perfectly coalesced writes through L2). Grid = B * 128 = 512 blocks.
// ---------------------------------------------------------------------------
__global__ __launch_bounds__(256) void gather_kernel(
    const float* __restrict__ feat,   // [B][64][Np]
    const float* __restrict__ temb,   // [B][64][Np]
    const int*   __restrict__ idxs,   // [B*Nq][K] resolved
    float* __restrict__ out)
{
    const int blk = blockIdx.x;        // 0 .. 511
    const int b   = blk >> 7;
    const int j   = blk & 127;         // 0..63 feat, 64..127 temb

    const float* src;
    float* dst;
    if (j < 64) {
        src = feat + ((size_t)b * 64 + j) * kNp;
        dst = out + (size_t)(b * 67 + 3 + j) * (kNq * kK);
    } else {
        src = temb + ((size_t)b * 64 + (j - 64)) * kNp;
        dst = out + (size_t)kB * 67 * kNq * kK
                  + (size_t)(b * 64 + (j - 64)) * (kNq * kK);
    }

    __shared__ float row[kNp];         // 32 KB
    {
        const v4f* s4 = (const v4f*)src;
        v4f* r4 = (v4f*)row;
#pragma unroll
        for (int i = 0; i < kNp / 4 / 256; ++i)     // 8 iters
            r4[i * 256 + threadIdx.x] = s4[i * 256 + threadIdx.x];
    }
    __syncthreads();

    const v4i* id4 = (const v4i*)(idxs + (size_t)b * kNq * kK);
    v4f* d4 = (v4f*)dst;
    constexpr int total4 = kNq * kK / 4;            // 16384
#pragma unroll 4
    for (int e = threadIdx.x; e < total4; e += 256) {
        const v4i id = id4[e];
        v4f v;
        v.x = row[id.x];
        v.y = row[id.y];
        v.z = row[id.z];
        v.w = row[id.w];
        d4[e] = v;
    }
}

// ---------------------------------------------------------------------------
extern "C" void kernel_launch(void* const* d_in, const int* in_sizes, int n_in,
                              void* d_out, int out_size, void* d_ws, size_t ws_size,
                              hipStream_t stream) {
    const float* coords  = (const float*)d_in[0];  // [B,Np,3]
    const float* feats   = (const float*)d_in[1];  // [B,64,Np]
    const float* temb    = (const float*)d_in[2];  // [B,64,Np]
    const float* queries = (const float*)d_in[3];  // [B,Nq,3]
    float* out = (float*)d_out;

    int* idxs = (int*)d_ws;                        // 1 MB scratch

    ball_query_kernel<<<kB * kNq / 4, 256, 0, stream>>>(coords, queries, idxs, out);
    gather_kernel<<<kB * 128, 256, 0, stream>>>(feats, temb, idxs, out);
}

// Round 7
// 178.536 us; speedup vs baseline: 1.1291x; 1.1157x over previous
//
#include <hip/hip_runtime.h>

// Problem constants (fixed by setup_inputs)
constexpr int kB  = 4;
constexpr int kNp = 8192;
constexpr int kNq = 2048;
constexpr int kK  = 32;   // max samples per query
constexpr float kR2 = (float)(0.2 * 0.2);   // matches numpy f32(radius*radius)

// Native clang vector types (HIP's float4/int4 are classes; ext-vectors map
// directly onto dwordx4 loads/stores).
typedef float v4f __attribute__((ext_vector_type(4)));
typedef int   v4i __attribute__((ext_vector_type(4)));

// ---------------------------------------------------------------------------
// Kernel A: coords [B][Np][3] -> SoA cb3 [B][3][Np]. SoA is required: AoS
// lane-stride-12 loads touch 12 cache lines/instr (3x the line-transactions);
// measured +14us on the ball query (round 2 vs 5 A/B).
// ---------------------------------------------------------------------------
__global__ __launch_bounds__(256) void coords_soa_kernel(
    const float* __restrict__ coords, float* __restrict__ cb3)
{
    const int t = blockIdx.x * 256 + threadIdx.x;   // 0 .. B*Np-1
    const int b = t >> 13;                          // / Np
    const int p = t & (kNp - 1);
    const float x = coords[(size_t)t * 3 + 0];
    const float y = coords[(size_t)t * 3 + 1];
    const float z = coords[(size_t)t * 3 + 2];
    float* o = cb3 + (size_t)b * 3 * kNp;
    o[0 * kNp + p] = x;
    o[1 * kNp + p] = y;
    o[2 * kNp + p] = z;
}

// ---------------------------------------------------------------------------
// Kernel B: ball query. One wave per query. Each iteration covers 256 points
// with 3 dwordx4 SoA loads (lane holds points 4*lane..4*lane+3). Four
// ballots (one per sub-element) + lane-major prefix arithmetic preserve
// exact first-K-in-index-order semantics; uniform early-exit per 256 points
// (same granularity as the verified round-2 kernel -> identical indices).
// Emits resolved idxs and the 3 centered-coords output channels.
// ---------------------------------------------------------------------------
__global__ __launch_bounds__(256) void ball_query_kernel(
    const float* __restrict__ cb3,      // [B][3][Np]
    const float* __restrict__ queries,  // [B][Nq][3]
    int* __restrict__ idxs,             // [B*Nq][K] (resolved, fill applied)
    float* __restrict__ out)            // full output tensor
{
    const int wave = (int)((blockIdx.x * blockDim.x + threadIdx.x) >> 6);
    const int lane = threadIdx.x & 63;
    const int w    = threadIdx.x >> 6;          // wave within block (0..3)
    const int b    = wave >> 11;                // / Nq
    const int q    = wave & (kNq - 1);

    const float qx = queries[(b * kNq + q) * 3 + 0];
    const float qy = queries[(b * kNq + q) * 3 + 1];
    const float qz = queries[(b * kNq + q) * 3 + 2];

    const float* __restrict__ cbx = cb3 + (size_t)b * 3 * kNp;
    const float* __restrict__ cby = cbx + kNp;
    const float* __restrict__ cbz = cby + kNp;
    const v4f* __restrict__ cbx4 = (const v4f*)cbx;
    const v4f* __restrict__ cby4 = (const v4f*)cby;
    const v4f* __restrict__ cbz4 = (const v4f*)cbz;

    __shared__ int s_idx[4][kK];   // per-wave private region; no barrier needed

    const unsigned long long lt = (1ull << lane) - 1ull;
    int cnt = 0;
    for (int base = 0; base < kNp; base += 256) {
        const int vi = (base >> 2) + lane;
        const v4f X = cbx4[vi];
        const v4f Y = cby4[vi];
        const v4f Z = cbz4[vi];

        bool in[4];
        unsigned long long m[4];
#pragma unroll
        for (int j = 0; j < 4; ++j) {
            // exact f32 per-op arithmetic (no fma contraction) to match numpy
            const float dx = __fsub_rn(qx, X[j]);
            const float dy = __fsub_rn(qy, Y[j]);
            const float dz = __fsub_rn(qz, Z[j]);
            const float d2 = __fadd_rn(
                __fadd_rn(__fmul_rn(dx, dx), __fmul_rn(dy, dy)),
                __fmul_rn(dz, dz));
            in[j] = d2 < kR2;
            m[j] = __ballot(in[j]);
        }

        // point index = base + 4*lane + j (lane-major): points before (lane,j)
        // are all of lanes<lane (any j) plus earlier j in this lane.
        int pre = cnt + __popcll(m[0] & lt) + __popcll(m[1] & lt)
                      + __popcll(m[2] & lt) + __popcll(m[3] & lt);
        int local = 0;
#pragma unroll
        for (int j = 0; j < 4; ++j) {
            if (in[j]) {
                const int slot = pre + local;
                if (slot < kK) s_idx[w][slot] = base + 4 * lane + j;
                ++local;
            }
        }
        cnt += __popcll(m[0]) + __popcll(m[1])
             + __popcll(m[2]) + __popcll(m[3]);     // wave-uniform
        if (cnt >= kK) break;                       // uniform branch
    }

    if (lane < kK) {
        int v;
        if (cnt == 0)        v = 0;
        else if (lane < cnt) v = s_idx[w][lane];
        else                 v = s_idx[w][0];       // fill with first valid
        idxs[(size_t)wave * kK + lane] = v;

        // centered-coords output channels 0..2 of grouped_features
        const int k = lane;
        float* gf = out + ((size_t)(b * 67) * kNq + q) * kK + k;
        gf[(size_t)0 * kNq * kK] = __fsub_rn(cbx[v], qx);
        gf[(size_t)1 * kNq * kK] = __fsub_rn(cby[v], qy);
        gf[(size_t)2 * kNq * kK] = __fsub_rn(cbz[v], qz);
    }
}

// ---------------------------------------------------------------------------
// Kernel C: scatter-free gather (round-2 proven config). One block per
// (b, source-channel): stage the 32KB channel row in LDS (coalesced 16B
// loads), then out[c][q][k] = row[idx] with 16B idx loads + plain 16B stores
// (perfectly coalesced writes through L2). Grid = B * 128 = 512 blocks.
// ---------------------------------------------------------------------------
__global__ __launch_bounds__(256) void gather_kernel(
    const float* __restrict__ feat,   // [B][64][Np]
    const float* __restrict__ temb,   // [B][64][Np]
    const int*   __restrict__ idxs,   // [B*Nq][K] resolved
    float* __restrict__ out)
{
    const int blk = blockIdx.x;        // 0 .. 511
    const int b   = blk >> 7;
    const int j   = blk & 127;         // 0..63 feat, 64..127 temb

    const float* src;
    float* dst;
    if (j < 64) {
        src = feat + ((size_t)b * 64 + j) * kNp;
        dst = out + (size_t)(b * 67 + 3 + j) * (kNq * kK);
    } else {
        src = temb + ((size_t)b * 64 + (j - 64)) * kNp;
        dst = out + (size_t)kB * 67 * kNq * kK
                  + (size_t)(b * 64 + (j - 64)) * (kNq * kK);
    }

    __shared__ float row[kNp];         // 32 KB
    {
        const v4f* s4 = (const v4f*)src;
        v4f* r4 = (v4f*)row;
#pragma unroll
        for (int i = 0; i < kNp / 4 / 256; ++i)     // 8 iters
            r4[i * 256 + threadIdx.x] = s4[i * 256 + threadIdx.x];
    }
    __syncthreads();

    const v4i* id4 = (const v4i*)(idxs + (size_t)b * kNq * kK);
    v4f* d4 = (v4f*)dst;
    constexpr int total4 = kNq * kK / 4;            // 16384
#pragma unroll 4
    for (int e = threadIdx.x; e < total4; e += 256) {
        const v4i id = id4[e];
        v4f v;
        v.x = row[id.x];
        v.y = row[id.y];
        v.z = row[id.z];
        v.w = row[id.w];
        d4[e] = v;
    }
}

// ---------------------------------------------------------------------------
extern "C" void kernel_launch(void* const* d_in, const int* in_sizes, int n_in,
                              void* d_out, int out_size, void* d_ws, size_t ws_size,
                              hipStream_t stream) {
    const float* coords  = (const float*)d_in[0];  // [B,Np,3]
    const float* feats   = (const float*)d_in[1];  // [B,64,Np]
    const float* temb    = (const float*)d_in[2];  // [B,64,Np]
    const float* queries = (const float*)d_in[3];  // [B,Nq,3]
    float* out = (float*)d_out;

    int*   idxs = (int*)d_ws;                                          // 1 MB
    float* cb3  = (float*)((char*)d_ws + (size_t)kB * kNq * kK * 4);   // 384 KB

    coords_soa_kernel<<<kB * kNp / 256, 256, 0, stream>>>(coords, cb3);
    ball_query_kernel<<<kB * kNq / 4, 256, 0, stream>>>(cb3, queries, idxs, out);
    gather_kernel<<<kB * 128, 256, 0, stream>>>(feats, temb, idxs, out);
}